// Round 11
// baseline (559.958 us; speedup 1.0000x reference)
//
#include <hip/hip_runtime.h>

typedef __attribute__((ext_vector_type(8))) short short8;
typedef __attribute__((ext_vector_type(4))) short short4v;
typedef __attribute__((ext_vector_type(4))) float floatx4;
typedef unsigned short u16;

#define MFMA16(a,b,c) __builtin_amdgcn_mfma_f32_16x16x32_bf16(a,b,c,0,0,0)

typedef const __attribute__((address_space(1))) void* gas1;
typedef __attribute__((address_space(3))) void* las3;
static __device__ __forceinline__ void glds16(const void* g, void* l){
  __builtin_amdgcn_global_load_lds((gas1)g, (las3)l, 16, 0, 0);
}

// fp32 -> bf16 round-to-nearest-even
static __device__ __forceinline__ u16 f2b(float f){
  union { float f; unsigned int u; } c; c.f = f;
  unsigned int u = c.u;
  u += 0x7fffu + ((u >> 16) & 1u);
  return (u16)(u >> 16);
}

// packed fp32x2 -> bf16x2 (RNE, same as f2b) in one instruction
static __device__ __forceinline__ unsigned int cvtpk(float lo, float hi){
  unsigned int r;
  asm("v_cvt_pk_bf16_f32 %0, %1, %2" : "=v"(r) : "v"(lo), "v"(hi));
  return r;
}

// ---- fused prep + LN1: 6 weight transposes + bias concat + layernorm(x) ----
// id < 12288: 32x32 transpose tiles; id == 12288: bias concat; id > 12288: LN1 row.
__global__ __launch_bounds__(256) void prep_ln_kernel(
    const float* __restrict__ Wq, const float* __restrict__ Wk,
    const float* __restrict__ Wv, const float* __restrict__ Wo,
    const float* __restrict__ Wfc, const float* __restrict__ Wpj,
    u16* __restrict__ Wqkvt, u16* __restrict__ Wot,
    u16* __restrict__ Wfct, u16* __restrict__ Wpjt,
    const float* __restrict__ bq, const float* __restrict__ bk,
    const float* __restrict__ bv, float* __restrict__ bqkv,
    const float* __restrict__ x, const float* __restrict__ g1,
    const float* __restrict__ b1, u16* __restrict__ xout)
{
  const int id = blockIdx.x;
  const int tid = threadIdx.x;
  if (id > 12288){
    // ---- LN1 row ----
    const int row = id - 12289;
    const float4 v = reinterpret_cast<const float4*>(x + (size_t)row * 1024)[tid];
    float s  = v.x + v.y + v.z + v.w;
    float s2 = v.x*v.x + v.y*v.y + v.z*v.z + v.w*v.w;
    #pragma unroll
    for (int off = 1; off < 64; off <<= 1){
      s  += __shfl_xor(s,  off);
      s2 += __shfl_xor(s2, off);
    }
    __shared__ float red[8];
    const int wave = tid >> 6, lane = tid & 63;
    if (lane == 0){ red[wave] = s; red[4 + wave] = s2; }
    __syncthreads();
    s  = red[0] + red[1] + red[2] + red[3];
    s2 = red[4] + red[5] + red[6] + red[7];
    const float mu  = s * (1.f/1024.f);
    const float var = s2 * (1.f/1024.f) - mu * mu;
    const float rs  = rsqrtf(var + 1e-5f);
    const float4 gg = reinterpret_cast<const float4*>(g1)[tid];
    const float4 bb = reinterpret_cast<const float4*>(b1)[tid];
    ushort4 o;
    o.x = f2b((v.x - mu) * rs * gg.x + bb.x);
    o.y = f2b((v.y - mu) * rs * gg.y + bb.y);
    o.z = f2b((v.z - mu) * rs * gg.z + bb.z);
    o.w = f2b((v.w - mu) * rs * gg.w + bb.w);
    reinterpret_cast<ushort4*>(xout + (size_t)row * 1024)[tid] = o;
    return;
  }
  if (id == 12288){
    for (int i = tid; i < 3072; i += 256)
      bqkv[i] = i < 1024 ? bq[i] : (i < 2048 ? bk[i - 1024] : bv[i - 2048]);
    return;
  }
  const float* W; u16* Wt; int K, N, loc, tshift;
  if (id < 4096){
    K = 1024; N = 1024; loc = id & 1023; tshift = 5;
    const int w = id >> 10;
    W  = (w == 0) ? Wq : (w == 1) ? Wk : (w == 2) ? Wv : Wo;
    Wt = (w == 3) ? Wot : Wqkvt + (size_t)w * 1024 * 1024;
  } else if (id < 8192){
    K = 1024; N = 4096; loc = id - 4096; tshift = 7; W = Wfc; Wt = Wfct;
  } else {
    K = 4096; N = 1024; loc = id - 8192; tshift = 5; W = Wpj; Wt = Wpjt;
  }
  const int nx = (loc & ((1 << tshift) - 1)) * 32;
  const int kx = (loc >> tshift) * 32;
  __shared__ float tile[32][33];
  const int tx = tid & 31, ty = tid >> 5;
  #pragma unroll
  for (int i = ty; i < 32; i += 8)
    tile[i][tx] = W[(size_t)(kx + i) * N + nx + tx];
  __syncthreads();
  #pragma unroll
  for (int i = ty; i < 32; i += 8)
    Wt[(size_t)(nx + i) * K + kx + tx] = f2b(tile[tx][i]);
}

// ---------------- layernorm fp32 -> bf16, C=1024, 1 block/row (LN2) ----------------
__global__ __launch_bounds__(256) void ln_kernel(
    const float* __restrict__ x, const float* __restrict__ g,
    const float* __restrict__ b, u16* __restrict__ out){
  const int row = blockIdx.x, tid = threadIdx.x;
  const float4 v = reinterpret_cast<const float4*>(x + (size_t)row * 1024)[tid];
  float s  = v.x + v.y + v.z + v.w;
  float s2 = v.x*v.x + v.y*v.y + v.z*v.z + v.w*v.w;
  #pragma unroll
  for (int off = 1; off < 64; off <<= 1){
    s  += __shfl_xor(s,  off);
    s2 += __shfl_xor(s2, off);
  }
  __shared__ float red[8];
  const int wave = tid >> 6, lane = tid & 63;
  if (lane == 0){ red[wave] = s; red[4 + wave] = s2; }
  __syncthreads();
  s  = red[0] + red[1] + red[2] + red[3];
  s2 = red[4] + red[5] + red[6] + red[7];
  const float mu  = s * (1.f/1024.f);
  const float var = s2 * (1.f/1024.f) - mu * mu;
  const float rs  = rsqrtf(var + 1e-5f);
  const float4 gg = reinterpret_cast<const float4*>(g)[tid];
  const float4 bb = reinterpret_cast<const float4*>(b)[tid];
  ushort4 o;
  o.x = f2b((v.x - mu) * rs * gg.x + bb.x);
  o.y = f2b((v.y - mu) * rs * gg.y + bb.y);
  o.z = f2b((v.z - mu) * rs * gg.z + bb.z);
  o.w = f2b((v.w - mu) * rs * gg.w + bb.w);
  reinterpret_cast<ushort4*>(out + (size_t)row * 1024)[tid] = o;
}

// ---------------- GEMM: 128x128 tile, BK=32 double-buffered, permuted-B epilogue ------
// QKVMODE: n0<1024 (Q columns) scaled by 0.125*log2(e) so attn uses exp2 directly.
template<bool GELU, bool RES, bool OUTBF, bool QKVMODE>
__global__ __launch_bounds__(256) void gemm128(
    const u16* __restrict__ A, const u16* __restrict__ Bt,
    const float* __restrict__ bias,
    const float* __restrict__ res,
    float* __restrict__ outF, u16* __restrict__ outB,
    u16* __restrict__ vtb,
    int M, int N, int K)
{
  __shared__ __attribute__((aligned(16))) u16 sA[2][128 * 32];
  __shared__ __attribute__((aligned(16))) u16 sB[2][128 * 32];
  const int tid  = threadIdx.x;
  const int wave = tid >> 6, lane = tid & 63, quad = lane >> 4, l16 = lane & 15;
  const int m0 = blockIdx.x * 128, n0 = blockIdx.y * 128;
  const int wm = (wave >> 1) * 64, wn = (wave & 1) * 64;

  const int scol = ((lane & 3) ^ ((lane >> 3) & 3)) * 8;
  const size_t aoff  = (size_t)(m0 + wave*32 + (lane >> 2)) * K + scol;
  const size_t aoff2 = aoff + (size_t)16 * K;
  const int brow = n0 + (wave >> 1)*64 + 4*(lane >> 2) + (wave & 1)*2;
  const size_t boff  = (size_t)brow * K + scol;
  const size_t boff2 = boff + (size_t)K;
  u16* alp = sA[0] + wave * 1024;
  u16* blp = sB[0] + wave * 1024;
  const int qx = (quad ^ ((l16 >> 1) & 3)) * 8;

  floatx4 acc[4][4];
  #pragma unroll
  for (int i = 0; i < 4; i++)
    #pragma unroll
    for (int nt = 0; nt < 4; nt++) acc[i][nt] = floatx4{0.f,0.f,0.f,0.f};

  // prefetch k0 = 0 into buf 0
  glds16(A  + aoff,  alp);
  glds16(A  + aoff2, alp + 512);
  glds16(Bt + boff,  blp);
  glds16(Bt + boff2, blp + 512);

  int buf = 0;
  for (int k0 = 0; k0 < K; k0 += 32, buf ^= 1){
    __syncthreads();
    if (k0 + 32 < K){
      const int kn = k0 + 32;
      const int bo = (buf ^ 1) * 4096;
      glds16(A  + aoff  + kn, alp + bo);
      glds16(A  + aoff2 + kn, alp + bo + 512);
      glds16(Bt + boff  + kn, blp + bo);
      glds16(Bt + boff2 + kn, blp + bo + 512);
    }
    const u16* sa = sA[buf];
    const u16* sb = sB[buf];
    short8 af[4], bf[4];
    #pragma unroll
    for (int i = 0; i < 4; i++)
      af[i] = *reinterpret_cast<const short8*>(&sa[(wm + i*16 + l16)*32 + qx]);
    #pragma unroll
    for (int nt = 0; nt < 4; nt++)
      bf[nt] = *reinterpret_cast<const short8*>(&sb[(wn + nt*16 + l16)*32 + qx]);
    #pragma unroll
    for (int i = 0; i < 4; i++)
      #pragma unroll
      for (int nt = 0; nt < 4; nt++)
        acc[i][nt] = MFMA16(af[i], bf[nt], acc[i][nt]);
  }

  const int col0 = n0 + wn + 4*l16;   // lane's 4 columns: col0..col0+3
  const floatx4 bi = *reinterpret_cast<const floatx4*>(&bias[col0]);
  const float qsc = (QKVMODE && n0 < 1024) ? 0.18033688011112042f : 1.f;

  if (QKVMODE && n0 >= 2048){
    // V^T epilogue: vtb[bh][d][t], 4 consecutive t per lane -> packed 8B stores
    #pragma unroll
    for (int nt = 0; nt < 4; nt++){
      const int hd = col0 + nt - 2048;   // h*64 + d
      u16* vcol = vtb + (size_t)(hd >> 6) * 131072 + (size_t)(hd & 63) * 2048;
      #pragma unroll
      for (int i = 0; i < 4; i++){
        const int t0 = m0 + wm + i*16 + quad*4;      // global row (b,t)
        const int bb = t0 >> 11, tt = t0 & 2047;
        short4v pk;
        #pragma unroll
        for (int r = 0; r < 4; r++) pk[r] = (short)f2b(acc[i][nt][r] + bi[nt]);
        *reinterpret_cast<short4v*>(vcol + (size_t)bb * 2097152 + tt) = pk;
      }
    }
    return;
  }

  #pragma unroll
  for (int i = 0; i < 4; i++){
    #pragma unroll
    for (int r = 0; r < 4; r++){
      const int row = m0 + wm + i*16 + quad*4 + r;
      if (OUTBF){
        short4v o;
        #pragma unroll
        for (int nt = 0; nt < 4; nt++){
          float val = acc[i][nt][r] + bi[nt];
          if (GELU){
            const float t = 0.7978845608028654f * (val + 0.044715f * val * val * val);
            val = val / (1.f + __expf(-2.f * t));   // 0.5v(1+tanh t) == v*sigmoid(2t)
          }
          if (QKVMODE) val *= qsc;
          o[nt] = (short)f2b(val);
        }
        *reinterpret_cast<short4v*>(&outB[(size_t)row * N + col0]) = o;
      } else {
        floatx4 v;
        #pragma unroll
        for (int nt = 0; nt < 4; nt++) v[nt] = acc[i][nt][r] + bi[nt];
        if (RES){
          const floatx4 rr = *reinterpret_cast<const floatx4*>(&res[(size_t)row * N + col0]);
          #pragma unroll
          for (int nt = 0; nt < 4; nt++) v[nt] += rr[nt];
        }
        *reinterpret_cast<floatx4*>(&outF[(size_t)row * N + col0]) = v;
      }
    }
  }
}

// ---------------- flash attention, 8-wave blocks, causal, D=64, H=16, T=2048 --------
// 512 threads; 128 q-rows per block, ONE 16-row group per wave. K/V staging split
// across waves (waves 0-3 K, 4-7 V). V fragments read INLINE (r8 spill lesson).
// SPECULATIVE exp2: p = exp2(s - m_old) issued immediately (m_i init 0.0 as the
// deferred-max floor); local max tree runs in parallel; the rare growth branch
// (__any(local_max > m+6), wave-uniform) corrects via p *= alpha — never re-reads
// s, so NO extra register live-range. Masked keys: exp2(-1e30)=0. XCD head-pin
// remap; Q pre-scaled by 0.125*log2(e); cvtpk packs; setprio on MFMA.
// grid (16, 64) x 512
__global__ __launch_bounds__(512, 6) void attn_kernel(
    const u16* __restrict__ qkv, const u16* __restrict__ vtb,
    u16* __restrict__ O)
{
  constexpr int T = 2048, LDQ = 3072, LDP = 72;
  __shared__ __attribute__((aligned(16))) u16 sK[2][2][64*32];
  __shared__ __attribute__((aligned(16))) u16 sV[2][2][64*32];
  __shared__ __attribute__((aligned(16))) u16 sP[8][16*LDP];

  const int tid = threadIdx.x, wave = tid >> 6, lane = tid & 63;
  const int quad = lane >> 4, l16 = lane & 15;

  const int d  = blockIdx.y * 16 + blockIdx.x;
  const int r_ = d >> 3;
  const int hg = r_ >> 4, jj = r_ & 15;
  const int bh = (d & 7) * 8 + hg;               // 0..63
  const int qt = (hg & 2) ? (15 - jj) : jj;
  const int q0 = qt * 128;
  const int b = bh >> 4, h = bh & 15;

  const u16* Qp = qkv + (size_t)b * T * LDQ + h * 64;
  const u16* Kp = Qp + 1024;
  const u16* Vt = vtb + (size_t)bh * 64 * T;

  const int qx = (quad ^ ((l16 >> 1) & 3)) * 8;   // swizzled fragment chunk

  const int kq = q0 + wave * 16;        // wave's first q-row
  const int qg = kq + l16;              // this lane's q-row
  const short8 qf0 = *reinterpret_cast<const short8*>(&Qp[(size_t)qg*LDQ + quad*8]);
  const short8 qf1 = *reinterpret_cast<const short8*>(&Qp[(size_t)qg*LDQ + 32 + quad*8]);

  // m_i = 0.0f: deferred-max floor (scores |s|<~5 after prescale; fast-path p<=2^6;
  // overflow would need s>127 — ~25x margin). NOT -inf (spec exp2 would hit inf*0).
  float m_i = 0.f, l_i = 0.f;
  floatx4 o_acc[4];
  #pragma unroll
  for (int nt = 0; nt < 4; nt++) o_acc[nt] = floatx4{0.f,0.f,0.f,0.f};

  // staging duty: waves 0-3 -> K rows, waves 4-7 -> V rows (same swizzled layout)
  const int sw = wave & 3;
  const int srow = sw*16 + (lane >> 2);
  const int scol = ((lane & 3) ^ ((lane >> 3) & 3)) * 8;
  const bool isK = wave < 4;
  const u16* g0 = isK ? (Kp + (size_t)srow*LDQ + scol) : (Vt + (size_t)srow*T + scol);
  const u16* g1 = g0 + 32;
  const size_t gs = isK ? (size_t)LDQ : (size_t)1;   // per-key advance
  u16* l0 = (isK ? &sK[0][0][0] : &sV[0][0][0]) + sw*512;
  u16* l1 = (isK ? &sK[0][1][0] : &sV[0][1][0]) + sw*512;

  // prefetch tile 0 into buf 0
  glds16(g0, l0);
  glds16(g1, l1);

  const int asrc = (lane & 48) | (quad * 4);   // shfl src: lane owning q-row quad*4+r
  const int kend = q0 + 128;

  int buf = 0;
  for (int k0 = 0; k0 < kend; k0 += 64, buf ^= 1){
    __syncthreads();   // tile `buf` staged; buf^1 free
    if (k0 + 64 < kend){
      const size_t adv = (size_t)(k0 + 64) * gs;
      glds16(g0 + adv, l0 + (buf ^ 1) * 4096);
      glds16(g1 + adv, l1 + (buf ^ 1) * 4096);
    }

    if (k0 <= kq + 15){     // wave has unmasked keys in this tile
      // S^T = K·Q^T : s[sub][r] = score(key = k0+sub*16+quad*4+r, q = qg)
      float s[4][4];
      __builtin_amdgcn_s_setprio(1);
      #pragma unroll
      for (int sub = 0; sub < 4; sub++){
        const short8 kf0 = *reinterpret_cast<const short8*>(&sK[buf][0][(sub*16 + l16)*32 + qx]);
        const short8 kf1 = *reinterpret_cast<const short8*>(&sK[buf][1][(sub*16 + l16)*32 + qx]);
        floatx4 sa = MFMA16(kf0, qf0, (floatx4{0.f,0.f,0.f,0.f}));
        sa = MFMA16(kf1, qf1, sa);
        #pragma unroll
        for (int r = 0; r < 4; r++) s[sub][r] = sa[r];
      }
      __builtin_amdgcn_s_setprio(0);

      if (k0 + 63 > kq){    // diagonal region for this wave
        #pragma unroll
        for (int sub = 0; sub < 4; sub++)
          #pragma unroll
          for (int r = 0; r < 4; r++)
            if (k0 + sub*16 + quad*4 + r > qg) s[sub][r] = -1e30f;
      }

      // local max tree — independent of the exps below, runs in parallel
      float t0 = fmaxf(fmaxf(s[0][0],s[0][1]), fmaxf(s[0][2],s[0][3]));
      float t1 = fmaxf(fmaxf(s[1][0],s[1][1]), fmaxf(s[1][2],s[1][3]));
      float t2 = fmaxf(fmaxf(s[2][0],s[2][1]), fmaxf(s[2][2],s[2][3]));
      float t3 = fmaxf(fmaxf(s[3][0],s[3][1]), fmaxf(s[3][2],s[3][3]));
      const float mxl = fmaxf(fmaxf(t0,t1), fmaxf(t2,t3));

      // speculative exp2 with the OLD deferred max — no shuffles on this path
      #pragma unroll
      for (int sub = 0; sub < 4; sub++)
        #pragma unroll
        for (int r = 0; r < 4; r++)
          s[sub][r] = __builtin_amdgcn_exp2f(s[sub][r] - m_i);   // p in-place

      // rare growth: if no lane's LOCAL max exceeds m+6, no q-row's max does
      // (max-of-maxes). Branch is wave-uniform; correction is p *= alpha.
      if (__builtin_expect(__any(mxl > m_i + 6.f), 0)){
        float mx = fmaxf(mxl, __shfl_xor(mxl, 16));
        mx = fmaxf(mx, __shfl_xor(mx, 32));       // per-q-row max (quad group)
        const float mnew  = fmaxf(m_i, mx);
        const float alpha = __builtin_amdgcn_exp2f(m_i - mnew);
        #pragma unroll
        for (int sub = 0; sub < 4; sub++)
          #pragma unroll
          for (int r = 0; r < 4; r++) s[sub][r] *= alpha;   // exact correction
        float arow[4];
        #pragma unroll
        for (int r = 0; r < 4; r++) arow[r] = __shfl(alpha, asrc + r);
        #pragma unroll
        for (int nt = 0; nt < 4; nt++)
          #pragma unroll
          for (int r = 0; r < 4; r++) o_acc[nt][r] *= arow[r];
        l_i *= alpha;
        m_i = mnew;
      }

      float rA = (s[0][0]+s[0][1]) + (s[0][2]+s[0][3]);
      float rB = (s[1][0]+s[1][1]) + (s[1][2]+s[1][3]);
      float rC = (s[2][0]+s[2][1]) + (s[2][2]+s[2][3]);
      float rD = (s[3][0]+s[3][1]) + (s[3][2]+s[3][3]);
      float rowsum = (rA+rB) + (rC+rD);
      rowsum += __shfl_xor(rowsum, 16);
      rowsum += __shfl_xor(rowsum, 32);
      l_i += rowsum;

      // P -> sP in A-layout (row = q = l16, cols = key)
      #pragma unroll
      for (int sub = 0; sub < 4; sub++){
        uint2 pk2;
        pk2.x = cvtpk(s[sub][0], s[sub][1]);
        pk2.y = cvtpk(s[sub][2], s[sub][3]);
        *reinterpret_cast<uint2*>(&sP[wave][l16*LDP + sub*16 + quad*4]) = pk2;
      }
      const short8 pf0 = *reinterpret_cast<const short8*>(&sP[wave][l16*LDP + quad*8]);
      const short8 pf1 = *reinterpret_cast<const short8*>(&sP[wave][l16*LDP + 32 + quad*8]);

      __builtin_amdgcn_s_setprio(1);
      #pragma unroll
      for (int nt = 0; nt < 4; nt++){
        const short8 vf0 = *reinterpret_cast<const short8*>(&sV[buf][0][(nt*16 + l16)*32 + qx]);
        const short8 vf1 = *reinterpret_cast<const short8*>(&sV[buf][1][(nt*16 + l16)*32 + qx]);
        o_acc[nt] = MFMA16(pf0, vf0, o_acc[nt]);
        o_acc[nt] = MFMA16(pf1, vf1, o_acc[nt]);
      }
      __builtin_amdgcn_s_setprio(0);
    }
  }

  float lrow[4];
  #pragma unroll
  for (int r = 0; r < 4; r++) lrow[r] = __shfl(l_i, asrc + r);
  #pragma unroll
  for (int nt = 0; nt < 4; nt++){
    #pragma unroll
    for (int r = 0; r < 4; r++){
      const int row = kq + quad*4 + r;
      O[(size_t)(b*T + row)*1024 + h*64 + nt*16 + l16] = f2b(o_acc[nt][r] / lrow[r]);
    }
  }
}

// ---------------- launch ----------------
extern "C" void kernel_launch(void* const* d_in, const int* in_sizes, int n_in,
                              void* d_out, int out_size, void* d_ws, size_t ws_size,
                              hipStream_t stream){
  const float* x      = (const float*)d_in[0];
  const float* Wq     = (const float*)d_in[1];
  const float* bq     = (const float*)d_in[2];
  const float* Wk     = (const float*)d_in[3];
  const float* bk     = (const float*)d_in[4];
  const float* Wv     = (const float*)d_in[5];
  const float* bv     = (const float*)d_in[6];
  const float* Wo     = (const float*)d_in[7];
  const float* bo     = (const float*)d_in[8];
  const float* ln1_g  = (const float*)d_in[9];
  const float* ln1_b  = (const float*)d_in[10];
  const float* ln2_g  = (const float*)d_in[11];
  const float* ln2_b  = (const float*)d_in[12];
  const float* W_fc   = (const float*)d_in[13];
  const float* b_fc   = (const float*)d_in[14];
  const float* W_proj = (const float*)d_in[15];
  const float* b_proj = (const float*)d_in[16];
  float* out = (float*)d_out;
  char* ws = (char*)d_ws;
  const size_t MB = 1024 * 1024;

  u16* bufA  = (u16*)(ws);            // 16MB: xn -> attn_out -> h  [8192][1024]
  u16* qkvb  = (u16*)(ws + 16*MB);    // 48MB: [8192][3072] (V third unused)
  u16* vtb   = (u16*)(ws + 64*MB);    // 16MB: [64][64][2048] (written by QKV GEMM)
  u16* fcb   = (u16*)(ws + 16*MB);    // 64MB, reuses qkvb+vtb (dead after attn)
  float* x2  = out;                   // d_out doubles as fp32 residual buffer
  u16* Wqkvt = (u16*)(ws + 80*MB);    // 6MB: [3072][1024]
  u16* Wot   = (u16*)(ws + 86*MB);    // 2MB
  u16* Wfct  = (u16*)(ws + 88*MB);    // 8MB
  u16* Wpjt  = (u16*)(ws + 96*MB);    // 8MB
  float* bqkv= (float*)(ws + 104*MB); // 12KB

  dim3 tb(256);
  prep_ln_kernel<<<dim3(20481), tb, 0, stream>>>(
      Wq, Wk, Wv, Wo, W_fc, W_proj, Wqkvt, Wot, Wfct, Wpjt,
      bq, bk, bv, bqkv, x, ln1_g, ln1_b, bufA);

  // fused QKV: [8192,1024] @ [3072,1024]^T -> Q,K into qkvb; V^T into vtb
  gemm128<false,false,true,true><<<dim3(64,24), tb, 0, stream>>>(
      bufA, Wqkvt, bqkv, nullptr, nullptr, qkvb, vtb, 8192, 3072, 1024);

  attn_kernel<<<dim3(16, 64), dim3(512), 0, stream>>>(qkvb, vtb, bufA);

  gemm128<false,true,false,false><<<dim3(64,8), tb, 0, stream>>>(
      bufA, Wot, bo, x, x2, nullptr, nullptr, 8192, 1024, 1024);

  ln_kernel<<<8192, tb, 0, stream>>>(x2, ln2_g, ln2_b, bufA);

  gemm128<true,false,true,false><<<dim3(64,32), tb, 0, stream>>>(
      bufA, Wfct, b_fc, nullptr, nullptr, fcb, nullptr, 8192, 4096, 1024);

  gemm128<false,true,false,false><<<dim3(64,8), tb, 0, stream>>>(
      fcb, Wpjt, b_proj, x2, out, nullptr, nullptr, 8192, 1024, 4096);
}

// Round 12
// 503.530 us; speedup vs baseline: 1.1121x; 1.1121x over previous
//
#include <hip/hip_runtime.h>

typedef __attribute__((ext_vector_type(8))) short short8;
typedef __attribute__((ext_vector_type(4))) short short4v;
typedef __attribute__((ext_vector_type(4))) float floatx4;
typedef unsigned short u16;

#define MFMA16(a,b,c) __builtin_amdgcn_mfma_f32_16x16x32_bf16(a,b,c,0,0,0)

typedef const __attribute__((address_space(1))) void* gas1;
typedef __attribute__((address_space(3))) void* las3;
static __device__ __forceinline__ void glds16(const void* g, void* l){
  __builtin_amdgcn_global_load_lds((gas1)g, (las3)l, 16, 0, 0);
}

// fp32 -> bf16 round-to-nearest-even
static __device__ __forceinline__ u16 f2b(float f){
  union { float f; unsigned int u; } c; c.f = f;
  unsigned int u = c.u;
  u += 0x7fffu + ((u >> 16) & 1u);
  return (u16)(u >> 16);
}

// packed fp32x2 -> bf16x2 (RNE, same as f2b) in one instruction
static __device__ __forceinline__ unsigned int cvtpk(float lo, float hi){
  unsigned int r;
  asm("v_cvt_pk_bf16_f32 %0, %1, %2" : "=v"(r) : "v"(lo), "v"(hi));
  return r;
}

// ---- fused prep + LN1: 6 weight transposes + bias concat + layernorm(x) ----
// id < 12288: 32x32 transpose tiles; id == 12288: bias concat; id > 12288: LN1 row.
__global__ __launch_bounds__(256) void prep_ln_kernel(
    const float* __restrict__ Wq, const float* __restrict__ Wk,
    const float* __restrict__ Wv, const float* __restrict__ Wo,
    const float* __restrict__ Wfc, const float* __restrict__ Wpj,
    u16* __restrict__ Wqkvt, u16* __restrict__ Wot,
    u16* __restrict__ Wfct, u16* __restrict__ Wpjt,
    const float* __restrict__ bq, const float* __restrict__ bk,
    const float* __restrict__ bv, float* __restrict__ bqkv,
    const float* __restrict__ x, const float* __restrict__ g1,
    const float* __restrict__ b1, u16* __restrict__ xout)
{
  const int id = blockIdx.x;
  const int tid = threadIdx.x;
  if (id > 12288){
    // ---- LN1 row ----
    const int row = id - 12289;
    const float4 v = reinterpret_cast<const float4*>(x + (size_t)row * 1024)[tid];
    float s  = v.x + v.y + v.z + v.w;
    float s2 = v.x*v.x + v.y*v.y + v.z*v.z + v.w*v.w;
    #pragma unroll
    for (int off = 1; off < 64; off <<= 1){
      s  += __shfl_xor(s,  off);
      s2 += __shfl_xor(s2, off);
    }
    __shared__ float red[8];
    const int wave = tid >> 6, lane = tid & 63;
    if (lane == 0){ red[wave] = s; red[4 + wave] = s2; }
    __syncthreads();
    s  = red[0] + red[1] + red[2] + red[3];
    s2 = red[4] + red[5] + red[6] + red[7];
    const float mu  = s * (1.f/1024.f);
    const float var = s2 * (1.f/1024.f) - mu * mu;
    const float rs  = rsqrtf(var + 1e-5f);
    const float4 gg = reinterpret_cast<const float4*>(g1)[tid];
    const float4 bb = reinterpret_cast<const float4*>(b1)[tid];
    ushort4 o;
    o.x = f2b((v.x - mu) * rs * gg.x + bb.x);
    o.y = f2b((v.y - mu) * rs * gg.y + bb.y);
    o.z = f2b((v.z - mu) * rs * gg.z + bb.z);
    o.w = f2b((v.w - mu) * rs * gg.w + bb.w);
    reinterpret_cast<ushort4*>(xout + (size_t)row * 1024)[tid] = o;
    return;
  }
  if (id == 12288){
    for (int i = tid; i < 3072; i += 256)
      bqkv[i] = i < 1024 ? bq[i] : (i < 2048 ? bk[i - 1024] : bv[i - 2048]);
    return;
  }
  const float* W; u16* Wt; int K, N, loc, tshift;
  if (id < 4096){
    K = 1024; N = 1024; loc = id & 1023; tshift = 5;
    const int w = id >> 10;
    W  = (w == 0) ? Wq : (w == 1) ? Wk : (w == 2) ? Wv : Wo;
    Wt = (w == 3) ? Wot : Wqkvt + (size_t)w * 1024 * 1024;
  } else if (id < 8192){
    K = 1024; N = 4096; loc = id - 4096; tshift = 7; W = Wfc; Wt = Wfct;
  } else {
    K = 4096; N = 1024; loc = id - 8192; tshift = 5; W = Wpj; Wt = Wpjt;
  }
  const int nx = (loc & ((1 << tshift) - 1)) * 32;
  const int kx = (loc >> tshift) * 32;
  __shared__ float tile[32][33];
  const int tx = tid & 31, ty = tid >> 5;
  #pragma unroll
  for (int i = ty; i < 32; i += 8)
    tile[i][tx] = W[(size_t)(kx + i) * N + nx + tx];
  __syncthreads();
  #pragma unroll
  for (int i = ty; i < 32; i += 8)
    Wt[(size_t)(nx + i) * K + kx + tx] = f2b(tile[tx][i]);
}

// ---------------- layernorm fp32 -> bf16, C=1024, 1 block/row (LN2) ----------------
__global__ __launch_bounds__(256) void ln_kernel(
    const float* __restrict__ x, const float* __restrict__ g,
    const float* __restrict__ b, u16* __restrict__ out){
  const int row = blockIdx.x, tid = threadIdx.x;
  const float4 v = reinterpret_cast<const float4*>(x + (size_t)row * 1024)[tid];
  float s  = v.x + v.y + v.z + v.w;
  float s2 = v.x*v.x + v.y*v.y + v.z*v.z + v.w*v.w;
  #pragma unroll
  for (int off = 1; off < 64; off <<= 1){
    s  += __shfl_xor(s,  off);
    s2 += __shfl_xor(s2, off);
  }
  __shared__ float red[8];
  const int wave = tid >> 6, lane = tid & 63;
  if (lane == 0){ red[wave] = s; red[4 + wave] = s2; }
  __syncthreads();
  s  = red[0] + red[1] + red[2] + red[3];
  s2 = red[4] + red[5] + red[6] + red[7];
  const float mu  = s * (1.f/1024.f);
  const float var = s2 * (1.f/1024.f) - mu * mu;
  const float rs  = rsqrtf(var + 1e-5f);
  const float4 gg = reinterpret_cast<const float4*>(g)[tid];
  const float4 bb = reinterpret_cast<const float4*>(b)[tid];
  ushort4 o;
  o.x = f2b((v.x - mu) * rs * gg.x + bb.x);
  o.y = f2b((v.y - mu) * rs * gg.y + bb.y);
  o.z = f2b((v.z - mu) * rs * gg.z + bb.z);
  o.w = f2b((v.w - mu) * rs * gg.w + bb.w);
  reinterpret_cast<ushort4*>(out + (size_t)row * 1024)[tid] = o;
}

// ---------------- GEMM: 128x128 tile, BK=32 double-buffered, permuted-B epilogue ------
// QKVMODE: n0<1024 (Q columns) scaled by 0.125*log2(e) so attn uses exp2 directly.
template<bool GELU, bool RES, bool OUTBF, bool QKVMODE>
__global__ __launch_bounds__(256) void gemm128(
    const u16* __restrict__ A, const u16* __restrict__ Bt,
    const float* __restrict__ bias,
    const float* __restrict__ res,
    float* __restrict__ outF, u16* __restrict__ outB,
    u16* __restrict__ vtb,
    int M, int N, int K)
{
  __shared__ __attribute__((aligned(16))) u16 sA[2][128 * 32];
  __shared__ __attribute__((aligned(16))) u16 sB[2][128 * 32];
  const int tid  = threadIdx.x;
  const int wave = tid >> 6, lane = tid & 63, quad = lane >> 4, l16 = lane & 15;
  const int m0 = blockIdx.x * 128, n0 = blockIdx.y * 128;
  const int wm = (wave >> 1) * 64, wn = (wave & 1) * 64;

  const int scol = ((lane & 3) ^ ((lane >> 3) & 3)) * 8;
  const size_t aoff  = (size_t)(m0 + wave*32 + (lane >> 2)) * K + scol;
  const size_t aoff2 = aoff + (size_t)16 * K;
  const int brow = n0 + (wave >> 1)*64 + 4*(lane >> 2) + (wave & 1)*2;
  const size_t boff  = (size_t)brow * K + scol;
  const size_t boff2 = boff + (size_t)K;
  u16* alp = sA[0] + wave * 1024;
  u16* blp = sB[0] + wave * 1024;
  const int qx = (quad ^ ((l16 >> 1) & 3)) * 8;

  floatx4 acc[4][4];
  #pragma unroll
  for (int i = 0; i < 4; i++)
    #pragma unroll
    for (int nt = 0; nt < 4; nt++) acc[i][nt] = floatx4{0.f,0.f,0.f,0.f};

  // prefetch k0 = 0 into buf 0
  glds16(A  + aoff,  alp);
  glds16(A  + aoff2, alp + 512);
  glds16(Bt + boff,  blp);
  glds16(Bt + boff2, blp + 512);

  int buf = 0;
  for (int k0 = 0; k0 < K; k0 += 32, buf ^= 1){
    __syncthreads();
    if (k0 + 32 < K){
      const int kn = k0 + 32;
      const int bo = (buf ^ 1) * 4096;
      glds16(A  + aoff  + kn, alp + bo);
      glds16(A  + aoff2 + kn, alp + bo + 512);
      glds16(Bt + boff  + kn, blp + bo);
      glds16(Bt + boff2 + kn, blp + bo + 512);
    }
    const u16* sa = sA[buf];
    const u16* sb = sB[buf];
    short8 af[4], bf[4];
    #pragma unroll
    for (int i = 0; i < 4; i++)
      af[i] = *reinterpret_cast<const short8*>(&sa[(wm + i*16 + l16)*32 + qx]);
    #pragma unroll
    for (int nt = 0; nt < 4; nt++)
      bf[nt] = *reinterpret_cast<const short8*>(&sb[(wn + nt*16 + l16)*32 + qx]);
    #pragma unroll
    for (int i = 0; i < 4; i++)
      #pragma unroll
      for (int nt = 0; nt < 4; nt++)
        acc[i][nt] = MFMA16(af[i], bf[nt], acc[i][nt]);
  }

  const int col0 = n0 + wn + 4*l16;   // lane's 4 columns: col0..col0+3
  const floatx4 bi = *reinterpret_cast<const floatx4*>(&bias[col0]);
  const float qsc = (QKVMODE && n0 < 1024) ? 0.18033688011112042f : 1.f;

  if (QKVMODE && n0 >= 2048){
    // V^T epilogue: vtb[bh][d][t], 4 consecutive t per lane -> packed 8B stores
    #pragma unroll
    for (int nt = 0; nt < 4; nt++){
      const int hd = col0 + nt - 2048;   // h*64 + d
      u16* vcol = vtb + (size_t)(hd >> 6) * 131072 + (size_t)(hd & 63) * 2048;
      #pragma unroll
      for (int i = 0; i < 4; i++){
        const int t0 = m0 + wm + i*16 + quad*4;      // global row (b,t)
        const int bb = t0 >> 11, tt = t0 & 2047;
        short4v pk;
        #pragma unroll
        for (int r = 0; r < 4; r++) pk[r] = (short)f2b(acc[i][nt][r] + bi[nt]);
        *reinterpret_cast<short4v*>(vcol + (size_t)bb * 2097152 + tt) = pk;
      }
    }
    return;
  }

  #pragma unroll
  for (int i = 0; i < 4; i++){
    #pragma unroll
    for (int r = 0; r < 4; r++){
      const int row = m0 + wm + i*16 + quad*4 + r;
      if (OUTBF){
        short4v o;
        #pragma unroll
        for (int nt = 0; nt < 4; nt++){
          float val = acc[i][nt][r] + bi[nt];
          if (GELU){
            const float t = 0.7978845608028654f * (val + 0.044715f * val * val * val);
            val = val / (1.f + __expf(-2.f * t));   // 0.5v(1+tanh t) == v*sigmoid(2t)
          }
          if (QKVMODE) val *= qsc;
          o[nt] = (short)f2b(val);
        }
        *reinterpret_cast<short4v*>(&outB[(size_t)row * N + col0]) = o;
      } else {
        floatx4 v;
        #pragma unroll
        for (int nt = 0; nt < 4; nt++) v[nt] = acc[i][nt][r] + bi[nt];
        if (RES){
          const floatx4 rr = *reinterpret_cast<const floatx4*>(&res[(size_t)row * N + col0]);
          #pragma unroll
          for (int nt = 0; nt < 4; nt++) v[nt] += rr[nt];
        }
        *reinterpret_cast<floatx4*>(&outF[(size_t)row * N + col0]) = v;
      }
    }
  }
}

// ---------------- flash attention, 8-wave blocks, causal, D=64, H=16, T=2048 --------
// 512 threads; 128 q-rows per block, ONE 16-row group per wave. K/V staging split
// across waves (waves 0-3 K, 4-7 V). V fragments read INLINE in the PV loop.
// PROVEN r10 softmax ordering (both the r6 batch-restructure and the r11
// speculative-exp2 variants SPILLED under launch_bounds(512,6): VGPR 40,
// WRITE 97-239MB — do not extend >8 f32 live ranges across a branch here).
// XCD head-pin remap; Q pre-scaled; defer-max THR=6; cvtpk packs; setprio.
// grid (16, 64) x 512
__global__ __launch_bounds__(512, 6) void attn_kernel(
    const u16* __restrict__ qkv, const u16* __restrict__ vtb,
    u16* __restrict__ O)
{
  constexpr int T = 2048, LDQ = 3072, LDP = 72;
  __shared__ __attribute__((aligned(16))) u16 sK[2][2][64*32];
  __shared__ __attribute__((aligned(16))) u16 sV[2][2][64*32];
  __shared__ __attribute__((aligned(16))) u16 sP[8][16*LDP];

  const int tid = threadIdx.x, wave = tid >> 6, lane = tid & 63;
  const int quad = lane >> 4, l16 = lane & 15;

  const int d  = blockIdx.y * 16 + blockIdx.x;
  const int r_ = d >> 3;
  const int hg = r_ >> 4, jj = r_ & 15;
  const int bh = (d & 7) * 8 + hg;               // 0..63
  const int qt = (hg & 2) ? (15 - jj) : jj;
  const int q0 = qt * 128;
  const int b = bh >> 4, h = bh & 15;

  const u16* Qp = qkv + (size_t)b * T * LDQ + h * 64;
  const u16* Kp = Qp + 1024;
  const u16* Vt = vtb + (size_t)bh * 64 * T;

  const int qx = (quad ^ ((l16 >> 1) & 3)) * 8;   // swizzled fragment chunk

  const int kq = q0 + wave * 16;        // wave's first q-row
  const int qg = kq + l16;              // this lane's q-row
  const short8 qf0 = *reinterpret_cast<const short8*>(&Qp[(size_t)qg*LDQ + quad*8]);
  const short8 qf1 = *reinterpret_cast<const short8*>(&Qp[(size_t)qg*LDQ + 32 + quad*8]);

  float m_i = -INFINITY, l_i = 0.f;
  floatx4 o_acc[4];
  #pragma unroll
  for (int nt = 0; nt < 4; nt++) o_acc[nt] = floatx4{0.f,0.f,0.f,0.f};

  // staging duty: waves 0-3 -> K rows, waves 4-7 -> V rows (same swizzled layout)
  const int sw = wave & 3;
  const int srow = sw*16 + (lane >> 2);
  const int scol = ((lane & 3) ^ ((lane >> 3) & 3)) * 8;
  const bool isK = wave < 4;
  const u16* g0 = isK ? (Kp + (size_t)srow*LDQ + scol) : (Vt + (size_t)srow*T + scol);
  const u16* g1 = g0 + 32;
  const size_t gs = isK ? (size_t)LDQ : (size_t)1;   // per-key advance
  u16* l0 = (isK ? &sK[0][0][0] : &sV[0][0][0]) + sw*512;
  u16* l1 = (isK ? &sK[0][1][0] : &sV[0][1][0]) + sw*512;

  // prefetch tile 0 into buf 0
  glds16(g0, l0);
  glds16(g1, l1);

  const int asrc = (lane & 48) | (quad * 4);   // shfl src: lane owning q-row quad*4+r
  const int kend = q0 + 128;

  int buf = 0;
  for (int k0 = 0; k0 < kend; k0 += 64, buf ^= 1){
    __syncthreads();   // tile `buf` staged; buf^1 free
    if (k0 + 64 < kend){
      const size_t adv = (size_t)(k0 + 64) * gs;
      glds16(g0 + adv, l0 + (buf ^ 1) * 4096);
      glds16(g1 + adv, l1 + (buf ^ 1) * 4096);
    }

    if (k0 <= kq + 15){     // wave has unmasked keys in this tile
      // S^T = K·Q^T : s[sub][r] = score(key = k0+sub*16+quad*4+r, q = qg)
      float s[4][4];
      __builtin_amdgcn_s_setprio(1);
      #pragma unroll
      for (int sub = 0; sub < 4; sub++){
        const short8 kf0 = *reinterpret_cast<const short8*>(&sK[buf][0][(sub*16 + l16)*32 + qx]);
        const short8 kf1 = *reinterpret_cast<const short8*>(&sK[buf][1][(sub*16 + l16)*32 + qx]);
        floatx4 sa = MFMA16(kf0, qf0, (floatx4{0.f,0.f,0.f,0.f}));
        sa = MFMA16(kf1, qf1, sa);
        #pragma unroll
        for (int r = 0; r < 4; r++) s[sub][r] = sa[r];
      }
      __builtin_amdgcn_s_setprio(0);

      if (k0 + 63 > kq){    // diagonal region for this wave
        #pragma unroll
        for (int sub = 0; sub < 4; sub++)
          #pragma unroll
          for (int r = 0; r < 4; r++)
            if (k0 + sub*16 + quad*4 + r > qg) s[sub][r] = -1e30f;
      }

      // tree max + cross-quad reduce
      float t0 = fmaxf(fmaxf(s[0][0],s[0][1]), fmaxf(s[0][2],s[0][3]));
      float t1 = fmaxf(fmaxf(s[1][0],s[1][1]), fmaxf(s[1][2],s[1][3]));
      float t2 = fmaxf(fmaxf(s[2][0],s[2][1]), fmaxf(s[2][2],s[2][3]));
      float t3 = fmaxf(fmaxf(s[3][0],s[3][1]), fmaxf(s[3][2],s[3][3]));
      float mx = fmaxf(fmaxf(t0,t1), fmaxf(t2,t3));
      mx = fmaxf(mx, __shfl_xor(mx, 16));
      mx = fmaxf(mx, __shfl_xor(mx, 32));

      // defer-max: keep old max unless growth > 6 (exp2 domain; P <= 64, safe)
      const bool up = mx > m_i + 6.f;
      const float mnew = up ? mx : m_i;

      #pragma unroll
      for (int sub = 0; sub < 4; sub++)
        #pragma unroll
        for (int r = 0; r < 4; r++)
          s[sub][r] = __builtin_amdgcn_exp2f(s[sub][r] - mnew);   // p in-place

      float rA = (s[0][0]+s[0][1]) + (s[0][2]+s[0][3]);
      float rB = (s[1][0]+s[1][1]) + (s[1][2]+s[1][3]);
      float rC = (s[2][0]+s[2][1]) + (s[2][2]+s[2][3]);
      float rD = (s[3][0]+s[3][1]) + (s[3][2]+s[3][3]);
      float rowsum = (rA+rB) + (rC+rD);
      rowsum += __shfl_xor(rowsum, 16);
      rowsum += __shfl_xor(rowsum, 32);

      if (__any(up)){                    // wave-uniform rescale branch
        const float alpha = up ? __builtin_amdgcn_exp2f(m_i - mnew) : 1.f;
        float arow[4];
        #pragma unroll
        for (int r = 0; r < 4; r++) arow[r] = __shfl(alpha, asrc + r);
        #pragma unroll
        for (int nt = 0; nt < 4; nt++)
          #pragma unroll
          for (int r = 0; r < 4; r++) o_acc[nt][r] *= arow[r];
        l_i *= alpha;
        m_i = mnew;
      }
      l_i += rowsum;

      // P -> sP in A-layout (row = q = l16, cols = key)
      #pragma unroll
      for (int sub = 0; sub < 4; sub++){
        uint2 pk2;
        pk2.x = cvtpk(s[sub][0], s[sub][1]);
        pk2.y = cvtpk(s[sub][2], s[sub][3]);
        *reinterpret_cast<uint2*>(&sP[wave][l16*LDP + sub*16 + quad*4]) = pk2;
      }
      const short8 pf0 = *reinterpret_cast<const short8*>(&sP[wave][l16*LDP + quad*8]);
      const short8 pf1 = *reinterpret_cast<const short8*>(&sP[wave][l16*LDP + 32 + quad*8]);

      __builtin_amdgcn_s_setprio(1);
      #pragma unroll
      for (int nt = 0; nt < 4; nt++){
        const short8 vf0 = *reinterpret_cast<const short8*>(&sV[buf][0][(nt*16 + l16)*32 + qx]);
        const short8 vf1 = *reinterpret_cast<const short8*>(&sV[buf][1][(nt*16 + l16)*32 + qx]);
        o_acc[nt] = MFMA16(pf0, vf0, o_acc[nt]);
        o_acc[nt] = MFMA16(pf1, vf1, o_acc[nt]);
      }
      __builtin_amdgcn_s_setprio(0);
    }
  }

  float lrow[4];
  #pragma unroll
  for (int r = 0; r < 4; r++) lrow[r] = __shfl(l_i, asrc + r);
  #pragma unroll
  for (int nt = 0; nt < 4; nt++){
    #pragma unroll
    for (int r = 0; r < 4; r++){
      const int row = kq + quad*4 + r;
      O[(size_t)(b*T + row)*1024 + h*64 + nt*16 + l16] = f2b(o_acc[nt][r] / lrow[r]);
    }
  }
}

// ---------------- launch ----------------
extern "C" void kernel_launch(void* const* d_in, const int* in_sizes, int n_in,
                              void* d_out, int out_size, void* d_ws, size_t ws_size,
                              hipStream_t stream){
  const float* x      = (const float*)d_in[0];
  const float* Wq     = (const float*)d_in[1];
  const float* bq     = (const float*)d_in[2];
  const float* Wk     = (const float*)d_in[3];
  const float* bk     = (const float*)d_in[4];
  const float* Wv     = (const float*)d_in[5];
  const float* bv     = (const float*)d_in[6];
  const float* Wo     = (const float*)d_in[7];
  const float* bo     = (const float*)d_in[8];
  const float* ln1_g  = (const float*)d_in[9];
  const float* ln1_b  = (const float*)d_in[10];
  const float* ln2_g  = (const float*)d_in[11];
  const float* ln2_b  = (const float*)d_in[12];
  const float* W_fc   = (const float*)d_in[13];
  const float* b_fc   = (const float*)d_in[14];
  const float* W_proj = (const float*)d_in[15];
  const float* b_proj = (const float*)d_in[16];
  float* out = (float*)d_out;
  char* ws = (char*)d_ws;
  const size_t MB = 1024 * 1024;

  u16* bufA  = (u16*)(ws);            // 16MB: xn -> attn_out -> h  [8192][1024]
  u16* qkvb  = (u16*)(ws + 16*MB);    // 48MB: [8192][3072] (V third unused)
  u16* vtb   = (u16*)(ws + 64*MB);    // 16MB: [64][64][2048] (written by QKV GEMM)
  u16* fcb   = (u16*)(ws + 16*MB);    // 64MB, reuses qkvb+vtb (dead after attn)
  float* x2  = out;                   // d_out doubles as fp32 residual buffer
  u16* Wqkvt = (u16*)(ws + 80*MB);    // 6MB: [3072][1024]
  u16* Wot   = (u16*)(ws + 86*MB);    // 2MB
  u16* Wfct  = (u16*)(ws + 88*MB);    // 8MB
  u16* Wpjt  = (u16*)(ws + 96*MB);    // 8MB
  float* bqkv= (float*)(ws + 104*MB); // 12KB

  dim3 tb(256);
  prep_ln_kernel<<<dim3(20481), tb, 0, stream>>>(
      Wq, Wk, Wv, Wo, W_fc, W_proj, Wqkvt, Wot, Wfct, Wpjt,
      bq, bk, bv, bqkv, x, ln1_g, ln1_b, bufA);

  // fused QKV: [8192,1024] @ [3072,1024]^T -> Q,K into qkvb; V^T into vtb
  gemm128<false,false,true,true><<<dim3(64,24), tb, 0, stream>>>(
      bufA, Wqkvt, bqkv, nullptr, nullptr, qkvb, vtb, 8192, 3072, 1024);

  attn_kernel<<<dim3(16, 64), dim3(512), 0, stream>>>(qkvb, vtb, bufA);

  gemm128<false,true,false,false><<<dim3(64,8), tb, 0, stream>>>(
      bufA, Wot, bo, x, x2, nullptr, nullptr, 8192, 1024, 1024);

  ln_kernel<<<8192, tb, 0, stream>>>(x2, ln2_g, ln2_b, bufA);

  gemm128<true,false,true,false><<<dim3(64,32), tb, 0, stream>>>(
      bufA, Wfct, b_fc, nullptr, nullptr, fcb, nullptr, 8192, 4096, 1024);

  gemm128<false,true,false,false><<<dim3(64,8), tb, 0, stream>>>(
      fcb, Wpjt, b_proj, x2, out, nullptr, nullptr, 8192, 1024, 4096);
}